// Round 11
// baseline (309.369 us; speedup 1.0000x reference)
//
#include <hip/hip_runtime.h>
#include <stdint.h>

#define BATCH 8
#define NC 80
#define NA1 8112
#define NA2 2028
#define NA3 507
#define NTOT 10647
#define TILE 64
#define NTILES 167           /* ceil(10647/64) */
#define NSLOTS (NTILES*TILE) /* 10688 */
#define KSEL 256
#define MAXPC 100
#define MAXTOT 100
#define SCTHR 0.3f
#define IOUTHR 0.5f
#define KEYTHR 0xBE99999Au   /* okey(0.3f): candidate iff key > KEYTHR */
#define KEYBASE 0xBE99999Bu  /* rebased keys fit in 24 bits */

typedef unsigned long long ull;

// static device scratch; every word read was written THIS launch
__device__ ull g_cand[(size_t)BATCH * NC * NSLOTS];   // 54.7 MB, tile-compacted
__device__ unsigned g_tcnt[BATCH * NC * NTILES];      // per (class,tile) counts
__device__ unsigned g_hist[BATCH * NC * 256];         // per-class key-top-byte hist
__device__ ull g_ks[BATCH * NC * MAXPC];              // per-class kept, rank-sorted
__device__ unsigned g_kcnt[BATCH * NC];               // per-class kept count
__device__ unsigned g_fhist[BATCH * 256];             // per-image kept key hist

__device__ __forceinline__ unsigned okey(float f) {
  unsigned u = __float_as_uint(f);
  return u ^ ((unsigned)((int)u >> 31) | 0x80000000u);
}
__device__ __forceinline__ float inv_okey(unsigned k) {
  unsigned u = (k & 0x80000000u) ? (k ^ 0x80000000u) : ~k;
  return __uint_as_float(u);
}
__device__ __forceinline__ ull shflxor64(ull v, int m) {
  int lo = __shfl_xor((int)(unsigned)v, m, 64);
  int hi = __shfl_xor((int)(unsigned)(v >> 32), m, 64);
  return ((ull)(unsigned)hi << 32) | (unsigned)lo;
}
__device__ __forceinline__ unsigned wave_sufscan(unsigned v, int lane) {
  #pragma unroll
  for (int off = 1; off < 64; off <<= 1) {
    unsigned t = __shfl_down(v, off, 64);
    if (lane + off < 64) v += t;
  }
  return v;
}

// ---------- Kernel Z: zero the histogram arrays ----------
__global__ void zero_hists() {
  int i = blockIdx.x * 256 + threadIdx.x;
  if (i < BATCH * NC * 256) g_hist[i] = 0;
  if (i < BATCH * 256) g_fhist[i] = 0;
}

// ---------- Kernel A: scores + per-(class,tile) compaction + class hist ----------
__global__ __launch_bounds__(256)
void score_compact(const float* __restrict__ c1, const float* __restrict__ p1,
                   const float* __restrict__ c2, const float* __restrict__ p2,
                   const float* __restrict__ c3, const float* __restrict__ p3)
{
  const int tid = threadIdx.x;
  const int b = blockIdx.x / NTILES;
  const int t = blockIdx.x % NTILES;
  const int n0 = t * TILE;

  __shared__ float sp[TILE * 81];

  for (int e4 = tid; e4 < TILE * 20; e4 += 256) {
    int a = e4 / 20;
    int c4 = (e4 - a * 20) * 4;
    int ng = n0 + a;
    if (ng < NTOT) {
      const float* pp; int nl;
      if (ng < NA1)            { pp = p1 + (size_t)b * NA1 * NC; nl = ng; }
      else if (ng < NA1 + NA2) { pp = p2 + (size_t)b * NA2 * NC; nl = ng - NA1; }
      else                     { pp = p3 + (size_t)b * NA3 * NC; nl = ng - NA1 - NA2; }
      float4 pv = *(const float4*)(pp + (size_t)nl * NC + c4);
      sp[a * 81 + c4 + 0] = pv.x; sp[a * 81 + c4 + 1] = pv.y;
      sp[a * 81 + c4 + 2] = pv.z; sp[a * 81 + c4 + 3] = pv.w;
    }
  }
  __syncthreads();

  const int wv = tid >> 6, lane = tid & 63;
  const int ng = n0 + lane;
  const bool av = ng < NTOT;
  float cf = 0.0f;
  if (av) {
    if (ng < NA1)            cf = c1[b * NA1 + ng];
    else if (ng < NA1 + NA2) cf = c2[b * NA2 + ng - NA1];
    else                     cf = c3[b * NA3 + ng - NA1 - NA2];
  }
  for (int k = 0; k < 20; ++k) {
    int c = wv + 4 * k;
    float pv = av ? sp[lane * 81 + c] : 0.0f;
    unsigned key = okey(pv * cf);
    bool pred = av && (key > KEYTHR);
    ull m = __ballot(pred);
    if (pred) {
      unsigned pos = (unsigned)__popcll(m & ((1ull << lane) - 1ull));
      g_cand[((size_t)(b * NC + c) * NTILES + t) * TILE + pos] =
          ((ull)key << 32) | (unsigned)(~ng);
      atomicAdd(&g_hist[(b * NC + c) * 256 + ((key - KEYBASE) >> 16)], 1u);
    }
    if (lane == 0) g_tcnt[(b * NC + c) * NTILES + t] = (unsigned)__popcll(m);
  }
}

// ---------- Kernel B: per (b,c) hist-guided top-256 + sort + NMS ----------
__global__ __launch_bounds__(256)
void nms_per_class(const float* __restrict__ b1, const float* __restrict__ b2,
                   const float* __restrict__ b3)
{
  const int tid = threadIdx.x;
  const int lane = tid & 63, wv = tid >> 6;
  const int bc = blockIdx.x;
  const int b = bc / NC;
  const int c = bc - b * NC;

  __shared__ unsigned tc[NTILES];      // 668 B
  __shared__ unsigned suf[256];        // 1 KB
  __shared__ ull cand[KSEL];           // 2 KB
  __shared__ ull tie[KSEL];            // 2 KB
  __shared__ ull supp[KSEL * 5];       // 10 KB (stride 5: conflict-light)
  __shared__ float4 cbox[KSEL];        // 4 KB
  __shared__ ull kw[4], kfw[4];
  __shared__ unsigned s_sel[2], wtot[4];
  __shared__ int s_cgt, s_ceq;

  const ull* crow = g_cand + (size_t)bc * NSLOTS;

  cand[tid] = 0ull;
  if (tid == 0) { s_cgt = 0; s_ceq = 0; }
  if (tid < NTILES) tc[tid] = g_tcnt[bc * NTILES + tid];

  // histogram suffix scan: suf[t] = #candidates with bucket >= t
  unsigned hv = g_hist[bc * 256 + tid];
  unsigned v1 = wave_sufscan(hv, lane);
  if (lane == 0) wtot[wv] = v1;
  __syncthreads();
  {
    unsigned add = 0;
    for (int w = wv + 1; w < 4; ++w) add += wtot[w];
    v1 += add;
  }
  suf[tid] = v1;
  __syncthreads();
  const int total = (int)suf[0];
  const bool take_all = (total <= KSEL);
  {
    unsigned nxt = (tid == 255) ? 0u : suf[tid + 1];
    if (v1 >= KSEL && nxt < KSEL) { s_sel[0] = (unsigned)tid; s_sel[1] = nxt; }
  }
  __syncthreads();
  const int B1 = take_all ? -1 : (int)s_sel[0];
  const int n_gt = take_all ? 0 : (int)s_sel[1];
  const int need1 = KSEL - n_gt;

  // single filtered scan of the candidate row (8-wide chunks)
  for (int base = 0; base < NSLOTS; base += 2048) {
    ull v[8]; bool ok[8];
    #pragma unroll
    for (int e = 0; e < 8; ++e) {
      int s = base + e * 256 + tid;
      ok[e] = false;
      if (s < NSLOTS) {
        int t = s >> 6, j = s & 63;
        if (j < (int)tc[t]) { ok[e] = true; v[e] = crow[s]; }
      }
    }
    #pragma unroll
    for (int e = 0; e < 8; ++e) {
      unsigned bkt = ok[e] ? (((unsigned)(v[e] >> 32) - KEYBASE) >> 16) : 0u;
      bool toC = ok[e] && (take_all || (int)bkt > B1);
      bool toT = ok[e] && !take_all && ((int)bkt == B1);
      ull mg = __ballot(toC), mt = __ballot(toT);
      unsigned bg = 0, bt = 0;
      if (lane == 0) {
        if (mg) bg = (unsigned)atomicAdd(&s_cgt, (int)__popcll(mg));
        if (mt) bt = (unsigned)atomicAdd(&s_ceq, (int)__popcll(mt));
      }
      bg = (unsigned)__shfl((int)bg, 0, 64);
      bt = (unsigned)__shfl((int)bt, 0, 64);
      ull lt = (1ull << lane) - 1ull;
      if (toC) { unsigned p = bg + (unsigned)__popcll(mg & lt); if (p < KSEL) cand[p] = v[e]; }
      if (toT) { unsigned p = bt + (unsigned)__popcll(mt & lt); if (p < KSEL) tie[p] = v[e]; }
    }
  }
  __syncthreads();

  // exact tie resolution within boundary bucket (m small; O(m^2) parallel)
  {
    int m = s_ceq < KSEL ? s_ceq : KSEL;
    if (!take_all && tid < m) {
      ull e = tie[tid];
      int rank = 0;
      for (int i2 = 0; i2 < m; ++i2) rank += (tie[i2] > e) ? 1 : 0;
      if (rank < need1) cand[n_gt + rank] = e;
    }
  }
  __syncthreads();

  // bitonic sort 256 descending: registers + shfl; LDS only for j>=64
  ull v = cand[tid];
  for (int kk = 2; kk <= KSEL; kk <<= 1) {
    for (int j = kk >> 1; j > 0; j >>= 1) {
      ull o;
      if (j >= 64) {
        cand[tid] = v;
        __syncthreads();
        o = cand[tid ^ j];
        __syncthreads();
      } else {
        o = shflxor64(v, j);
      }
      bool keep_max = (((tid & j) == 0) == ((tid & kk) == 0));
      v = keep_max ? (v > o ? v : o) : (v < o ? v : o);
    }
  }

  {
    float4 bx = make_float4(0.f, 0.f, 0.f, 0.f);
    if (v != 0ull) {
      int myn = (int)(~(unsigned)v) & 0x3FFF;
      const float* bp;
      if (myn < NA1)            bp = b1 + (size_t)(b * NA1 + myn) * 4;
      else if (myn < NA1 + NA2) bp = b2 + (size_t)(b * NA2 + (myn - NA1)) * 4;
      else                      bp = b3 + (size_t)(b * NA3 + (myn - NA1 - NA2)) * 4;
      bx = make_float4(bp[0], bp[1], bp[2], bp[3]);
    }
    cbox[tid] = bx;
  }
  ull mvalid = __ballot(v != 0ull);
  if (lane == 0) kw[wv] = mvalid;
  __syncthreads();

  // suppression rows TRANSPOSED (thread j holds suppressor bits i<j),
  // but FIXED 256-trip loop so the compiler unrolls & batches LDS reads
  {
    const float4 mb = cbox[tid];
    const float myarea = (mb.z - mb.x) * (mb.w - mb.y);
    ull m0 = 0, m1 = 0, m2 = 0, m3 = 0;
    #pragma unroll 8
    for (int j = 0; j < KSEL; ++j) {
      float4 bj = cbox[j];
      float ja = (bj.z - bj.x) * (bj.w - bj.y);
      float iy = fmaxf(fminf(bj.z, mb.z) - fmaxf(bj.x, mb.x), 0.0f);
      float ix = fmaxf(fminf(bj.w, mb.w) - fmaxf(bj.y, mb.y), 0.0f);
      float inter = iy * ix;
      float uni = ja + myarea - inter;
      bool sup = (j < tid) && (uni > 0.0f) && (inter > IOUTHR * uni);
      ull bit = sup ? (1ull << (j & 63)) : 0ull;
      if ((j >> 6) == 0) m0 |= bit; else if ((j >> 6) == 1) m1 |= bit;
      else if ((j >> 6) == 2) m2 |= bit; else m3 |= bit;
    }
    supp[tid * 5 + 0] = m0; supp[tid * 5 + 1] = m1;
    supp[tid * 5 + 2] = m2; supp[tid * 5 + 3] = m3;
  }
  __syncthreads();

  // ballot-based greedy scan (wave 0): no ds_permute in the dependent chain
  if (wv == 0) {
    ull colw[4][4];
    #pragma unroll
    for (int q = 0; q < 4; ++q)
      #pragma unroll
      for (int w = 0; w < 4; ++w)
        colw[q][w] = supp[(q * 64 + lane) * 5 + w];
    bool alive[4], kept[4];
    #pragma unroll
    for (int q = 0; q < 4; ++q) {
      alive[q] = (kw[q] >> lane) & 1ull;
      kept[q] = false;
    }
    int run = 0;
    for (int w2 = 0; w2 < 4 && run < MAXPC; ++w2) {
      ull A = __ballot(alive[w2]);
      while (A != 0ull && run < MAXPC) {
        int ib = __ffsll((long long)A) - 1;
        if (lane == ib) kept[w2] = true;
        ++run;
        if (run >= MAXPC) break;
        #pragma unroll
        for (int q = 0; q < 4; ++q)
          alive[q] = alive[q] && !((colw[q][w2] >> ib) & 1ull);
        A = __ballot(alive[w2]);
        A = (ib >= 63) ? 0ull : (A & ~((2ull << ib) - 1ull));
      }
    }
    #pragma unroll
    for (int q = 0; q < 4; ++q) {
      ull f = __ballot(kept[q]);
      if (lane == 0) kfw[q] = f;
    }
  }
  __syncthreads();

  // write kept entries rank-sorted + per-image key histogram
  {
    ull w0 = kfw[0], w1 = kfw[1], w2 = kfw[2], w3 = kfw[3];
    int wq = tid >> 6, wb2 = tid & 63;
    ull myw = (wq == 0) ? w0 : (wq == 1) ? w1 : (wq == 2) ? w2 : w3;
    bool kept = (myw >> wb2) & 1ull;
    if (kept) {
      ull lt = (wb2 == 0) ? 0ull : (myw & ((1ull << wb2) - 1ull));
      int rank = __popcll(lt);
      if (wq > 0) rank += __popcll(w0);
      if (wq > 1) rank += __popcll(w1);
      if (wq > 2) rank += __popcll(w2);
      unsigned key24 = (unsigned)(v >> 32) - KEYBASE;
      unsigned n = (~(unsigned)v) & 0x3FFFu;
      ull e = ((ull)key24 << 40) | ((ull)(unsigned)(127 - c) << 33) |
              ((ull)(unsigned)(255 - tid) << 25) | n;
      g_ks[(size_t)bc * MAXPC + rank] = e;
      atomicAdd(&g_fhist[b * 256 + (key24 >> 16)], 1u);
    }
    if (tid == 0)
      g_kcnt[bc] = (unsigned)(__popcll(w0) + __popcll(w1) + __popcll(w2) + __popcll(w3));
  }
}

// ---------- Kernel C: per-image hist-guided top-100 + output ----------
__global__ __launch_bounds__(256)
void nms_final(const float* __restrict__ b1, const float* __restrict__ b2,
               const float* __restrict__ b3, float* __restrict__ out)
{
  const int tid = threadIdx.x;
  const int lane = tid & 63, wv = tid >> 6;
  const int b = blockIdx.x;
  __shared__ ull cand[128];
  __shared__ ull tie[512];
  __shared__ unsigned kc[NC];
  __shared__ unsigned suf[256];
  __shared__ unsigned s_sel[2], wtot[4];
  __shared__ int s_cgt, s_ceq;

  if (tid < 128) cand[tid] = 0ull;
  if (tid < NC) kc[tid] = g_kcnt[b * NC + tid];
  if (tid == 0) { s_cgt = 0; s_ceq = 0; }

  unsigned h = g_fhist[b * 256 + tid];
  unsigned v1 = wave_sufscan(h, lane);
  if (lane == 0) wtot[wv] = v1;
  __syncthreads();
  {
    unsigned add = 0;
    for (int w = wv + 1; w < 4; ++w) add += wtot[w];
    v1 += add;
  }
  suf[tid] = v1;
  __syncthreads();
  const int total = (int)suf[0];
  const bool take_all = (total <= MAXTOT);
  {
    unsigned nxt = (tid == 255) ? 0u : suf[tid + 1];
    if (v1 >= MAXTOT && nxt < MAXTOT) { s_sel[0] = (unsigned)tid; s_sel[1] = nxt; }
  }
  __syncthreads();
  const int B1 = take_all ? -1 : (int)s_sel[0];
  const int n_gt = take_all ? 0 : (int)s_sel[1];
  const int need = MAXTOT - n_gt;

  // parallel 8-wide scan over the 80*100 kept slots
  const ull* krow = g_ks + (size_t)b * NC * MAXPC;
  for (int base = 0; base < NC * MAXPC; base += 2048) {
    ull v[8]; bool ok[8];
    #pragma unroll
    for (int e = 0; e < 8; ++e) {
      int s = base + e * 256 + tid;
      ok[e] = false;
      if (s < NC * MAXPC) {
        int cc = s / MAXPC, j = s - cc * MAXPC;
        if (j < (int)kc[cc]) { ok[e] = true; v[e] = krow[s]; }
      }
    }
    #pragma unroll
    for (int e = 0; e < 8; ++e) {
      unsigned bkt = ok[e] ? (unsigned)(v[e] >> 56) : 0u;
      bool toC = ok[e] && (take_all || (int)bkt > B1);
      bool toT = ok[e] && !take_all && ((int)bkt == B1);
      ull mg = __ballot(toC), mt = __ballot(toT);
      unsigned bg = 0, bt = 0;
      if (lane == 0) {
        if (mg) bg = (unsigned)atomicAdd(&s_cgt, (int)__popcll(mg));
        if (mt) bt = (unsigned)atomicAdd(&s_ceq, (int)__popcll(mt));
      }
      bg = (unsigned)__shfl((int)bg, 0, 64);
      bt = (unsigned)__shfl((int)bt, 0, 64);
      ull lt = (1ull << lane) - 1ull;
      if (toC) { unsigned p = bg + (unsigned)__popcll(mg & lt); if (p < 128u) cand[p] = v[e]; }
      if (toT) { unsigned p = bt + (unsigned)__popcll(mt & lt); if (p < 512u) tie[p] = v[e]; }
    }
  }
  __syncthreads();

  // exact tie resolution
  {
    int m = s_ceq < 512 ? s_ceq : 512;
    if (!take_all && tid < m) {
      ull e = tie[tid];
      int rank = 0;
      for (int i2 = 0; i2 < m; ++i2) rank += (tie[i2] > e) ? 1 : 0;
      if (rank < need) cand[n_gt + rank] = e;
    }
    if (!take_all && tid >= m && 256 + tid < m) { /* unreachable; keep symmetry */ }
  }
  __syncthreads();
  // handle tie entries beyond thread count (m can exceed 256)
  {
    int m = s_ceq < 512 ? s_ceq : 512;
    for (int i = 256 + tid; i < m; i += 256) {
      ull e = tie[i];
      int rank = 0;
      for (int i2 = 0; i2 < m; ++i2) rank += (tie[i2] > e) ? 1 : 0;
      if (rank < need) cand[n_gt + rank] = e;
    }
  }
  __syncthreads();

  // bitonic sort 128 descending
  for (int kk = 2; kk <= 128; kk <<= 1) {
    for (int j = kk >> 1; j > 0; j >>= 1) {
      if (tid < 128) {
        int ixj = tid ^ j;
        if (ixj > tid) {
          ull a = cand[tid], c2 = cand[ixj];
          if (((tid & kk) == 0) ? (a < c2) : (a > c2)) { cand[tid] = c2; cand[ixj] = a; }
        }
      }
      __syncthreads();
    }
  }

  if (tid < MAXTOT) {
    ull e = cand[tid];
    float o0 = 0.f, o1 = 0.f, o2 = 0.f, o3 = 0.f, osc = 0.f, ocl = 0.f;
    if (e != 0ull) {
      unsigned key24 = (unsigned)(e >> 40);
      float sc = inv_okey(key24 + KEYBASE);
      int cls = 127 - (int)((e >> 33) & 127u);
      int n = (int)(e & 0x3FFFu);
      const float* bp;
      if (n < NA1)            bp = b1 + (size_t)(b * NA1 + n) * 4;
      else if (n < NA1 + NA2) bp = b2 + (size_t)(b * NA2 + (n - NA1)) * 4;
      else                    bp = b3 + (size_t)(b * NA3 + (n - NA1 - NA2)) * 4;
      o0 = fminf(fmaxf(bp[0], 0.0f), 1.0f);
      o1 = fminf(fmaxf(bp[1], 0.0f), 1.0f);
      o2 = fminf(fmaxf(bp[2], 0.0f), 1.0f);
      o3 = fminf(fmaxf(bp[3], 0.0f), 1.0f);
      osc = sc; ocl = (float)cls;
    }
    int oi = b * MAXTOT + tid;
    out[(size_t)oi * 4 + 0] = o0;
    out[(size_t)oi * 4 + 1] = o1;
    out[(size_t)oi * 4 + 2] = o2;
    out[(size_t)oi * 4 + 3] = o3;
    out[BATCH * MAXTOT * 4 + oi] = osc;
    out[BATCH * MAXTOT * 5 + oi] = ocl;
  }
  if (tid == 0) out[BATCH * MAXTOT * 6 + b] = (float)(total < MAXTOT ? total : MAXTOT);
}

extern "C" void kernel_launch(void* const* d_in, const int* in_sizes, int n_in,
                              void* d_out, int out_size, void* d_ws, size_t ws_size,
                              hipStream_t stream) {
  const float* b1 = (const float*)d_in[0];
  const float* c1 = (const float*)d_in[1];
  const float* p1 = (const float*)d_in[2];
  const float* b2 = (const float*)d_in[3];
  const float* c2 = (const float*)d_in[4];
  const float* p2 = (const float*)d_in[5];
  const float* b3 = (const float*)d_in[6];
  const float* c3 = (const float*)d_in[7];
  const float* p3 = (const float*)d_in[8];
  (void)in_sizes; (void)n_in; (void)out_size; (void)d_ws; (void)ws_size;

  zero_hists<<<dim3((BATCH * NC * 256 + 255) / 256), dim3(256), 0, stream>>>();
  score_compact<<<dim3(BATCH * NTILES), dim3(256), 0, stream>>>(c1, p1, c2, p2, c3, p3);
  nms_per_class<<<dim3(BATCH * NC), dim3(256), 0, stream>>>(b1, b2, b3);
  nms_final<<<dim3(BATCH), dim3(256), 0, stream>>>(b1, b2, b3, (float*)d_out);
}

// Round 12
// 218.838 us; speedup vs baseline: 1.4137x; 1.4137x over previous
//
#include <hip/hip_runtime.h>
#include <stdint.h>

#define BATCH 8
#define NC 80
#define NA1 8112
#define NA2 2028
#define NA3 507
#define NTOT 10647
#define TILE 64
#define NTILES 167           /* ceil(10647/64) */
#define NSLOTS (NTILES*TILE) /* 10688 */
#define KSEL 256
#define MAXPC 100
#define MAXTOT 100
#define SCTHR 0.3f
#define IOUTHR 0.5f
#define KEYTHR 0xBE99999Au   /* okey(0.3f): candidate iff key > KEYTHR */
#define KEYBASE 0xBE99999Bu  /* rebased keys fit in 24 bits */
#define STAGE_CAP 4608       /* E[cnt]=3609, sigma=49 -> 20 sigma margin */

typedef unsigned long long ull;

// static device scratch; every word read was written THIS launch
__device__ ull g_cand[(size_t)BATCH * NC * NSLOTS];   // 54.7 MB, tile-compacted
__device__ unsigned g_tcnt[BATCH * NC * NTILES];      // per (class,tile) counts
__device__ ull g_ks[BATCH * NC * MAXPC];              // per-class kept, rank-sorted
__device__ unsigned g_kcnt[BATCH * NC];               // per-class kept count

__device__ __forceinline__ unsigned okey(float f) {
  unsigned u = __float_as_uint(f);
  return u ^ ((unsigned)((int)u >> 31) | 0x80000000u);
}
__device__ __forceinline__ float inv_okey(unsigned k) {
  unsigned u = (k & 0x80000000u) ? (k ^ 0x80000000u) : ~k;
  return __uint_as_float(u);
}
__device__ __forceinline__ ull shflxor64(ull v, int m) {
  int lo = __shfl_xor((int)(unsigned)v, m, 64);
  int hi = __shfl_xor((int)(unsigned)(v >> 32), m, 64);
  return ((ull)(unsigned)hi << 32) | (unsigned)lo;
}
__device__ __forceinline__ ull bcast64(ull v, int src) {
  int lo = __shfl((int)(unsigned)v, src, 64);
  int hi = __shfl((int)(unsigned)(v >> 32), src, 64);
  return ((ull)(unsigned)hi << 32) | (unsigned)lo;
}
__device__ __forceinline__ unsigned wave_sufscan(unsigned v, int lane) {
  #pragma unroll
  for (int off = 1; off < 64; off <<= 1) {
    unsigned t = __shfl_down(v, off, 64);
    if (lane + off < 64) v += t;
  }
  return v;
}

// ---------- Kernel A: scores + per-(class,tile) compaction, no atomics ----------
__global__ __launch_bounds__(256)
void score_compact(const float* __restrict__ c1, const float* __restrict__ p1,
                   const float* __restrict__ c2, const float* __restrict__ p2,
                   const float* __restrict__ c3, const float* __restrict__ p3)
{
  const int tid = threadIdx.x;
  const int b = blockIdx.x / NTILES;
  const int t = blockIdx.x % NTILES;
  const int n0 = t * TILE;

  __shared__ float sp[TILE * 81];

  for (int e4 = tid; e4 < TILE * 20; e4 += 256) {
    int a = e4 / 20;
    int c4 = (e4 - a * 20) * 4;
    int ng = n0 + a;
    if (ng < NTOT) {
      const float* pp; int nl;
      if (ng < NA1)            { pp = p1 + (size_t)b * NA1 * NC; nl = ng; }
      else if (ng < NA1 + NA2) { pp = p2 + (size_t)b * NA2 * NC; nl = ng - NA1; }
      else                     { pp = p3 + (size_t)b * NA3 * NC; nl = ng - NA1 - NA2; }
      float4 pv = *(const float4*)(pp + (size_t)nl * NC + c4);
      sp[a * 81 + c4 + 0] = pv.x; sp[a * 81 + c4 + 1] = pv.y;
      sp[a * 81 + c4 + 2] = pv.z; sp[a * 81 + c4 + 3] = pv.w;
    }
  }
  __syncthreads();

  const int wv = tid >> 6, lane = tid & 63;
  const int ng = n0 + lane;
  const bool av = ng < NTOT;
  float cf = 0.0f;
  if (av) {
    if (ng < NA1)            cf = c1[b * NA1 + ng];
    else if (ng < NA1 + NA2) cf = c2[b * NA2 + ng - NA1];
    else                     cf = c3[b * NA3 + ng - NA1 - NA2];
  }
  for (int k = 0; k < 20; ++k) {
    int c = wv + 4 * k;
    float pv = av ? sp[lane * 81 + c] : 0.0f;
    unsigned key = okey(pv * cf);
    bool pred = av && (key > KEYTHR);
    ull m = __ballot(pred);
    if (pred) {
      unsigned pos = (unsigned)__popcll(m & ((1ull << lane) - 1ull));
      g_cand[((size_t)(b * NC + c) * NTILES + t) * TILE + pos] =
          ((ull)key << 32) | (unsigned)(~ng);
    }
    if (lane == 0) g_tcnt[(b * NC + c) * NTILES + t] = (unsigned)__popcll(m);
  }
}

// ---------- Kernel B: per (b,c) top-256 (1-pass hist) + sort + NMS ----------
__global__ __launch_bounds__(256)
void nms_per_class(const float* __restrict__ b1, const float* __restrict__ b2,
                   const float* __restrict__ b3)
{
  const int tid = threadIdx.x;
  const int lane = tid & 63, wv = tid >> 6;
  const int bc = blockIdx.x;
  const int b = bc / NC;
  const int c = bc - b * NC;

  __shared__ ull cstage[STAGE_CAP];            // 36864 B; aliased after death
  __shared__ unsigned tc[NTILES];
  __shared__ unsigned off[NTILES + 1];
  __shared__ unsigned hist4[1024];             // sub-hists, then alloc[256]
  __shared__ unsigned suf[256];
  __shared__ ull cand[KSEL];
  __shared__ ull tie[KSEL];
  __shared__ ull kw[4], kfw[4];
  __shared__ unsigned s_sel[4], wtot[4];
  ull* supp = cstage;                                   // 10240 B
  float4* cbox = (float4*)((char*)cstage + 10240);      // 4096 B

  const ull* crow = g_cand + (size_t)bc * NSLOTS;

  cand[tid] = 0ull;
  if (tid < NTILES) tc[tid] = g_tcnt[bc * NTILES + tid];
  __syncthreads();

  if (wv == 0) {                               // exclusive prefix over 167 counts
    unsigned carry = 0;
    for (int ch = 0; ch < 3; ++ch) {
      int idx = ch * 64 + lane;
      unsigned x = (idx < NTILES) ? tc[idx] : 0u;
      unsigned v = x;
      #pragma unroll
      for (int o = 1; o < 64; o <<= 1) {
        unsigned t2 = __shfl_up(v, o, 64);
        if (lane >= o) v += t2;
      }
      if (idx < NTILES) off[idx] = carry + v - x;
      carry += (unsigned)__shfl((int)v, 63, 64);
    }
    if (lane == 0) off[NTILES] = carry;
  }
  __syncthreads();
  const int cnt = (int)off[NTILES];
  const bool take_all = (cnt <= KSEL);
  const bool staged = !take_all && (cnt <= STAGE_CAP);

  // staging: 8-wide batched, independent-address writes (no atomic chain)
  for (int base = 0; base < NSLOTS; base += 2048) {
    ull v[8]; int pos[8]; bool ok[8];
    #pragma unroll
    for (int e = 0; e < 8; ++e) {
      int s = base + e * 256 + tid;
      ok[e] = false;
      if (s < NSLOTS) {
        int t = s >> 6, j = s & 63;
        if (j < (int)tc[t]) { ok[e] = true; pos[e] = (int)off[t] + j; v[e] = crow[s]; }
      }
    }
    #pragma unroll
    for (int e = 0; e < 8; ++e) {
      if (ok[e]) {
        if (take_all) cand[pos[e]] = v[e];
        else if (staged) cstage[pos[e]] = v[e];
      }
    }
  }
  __syncthreads();

  if (!take_all) {
    // one-pass byte histogram (rebased key >> 16), per-wave sub-hists
    hist4[tid] = 0; hist4[tid + 256] = 0; hist4[tid + 512] = 0; hist4[tid + 768] = 0;
    __syncthreads();
    const int wb = wv << 8;
    if (staged) {
      for (int i = tid; i < cnt; i += 256)
        atomicAdd(&hist4[wb + ((((unsigned)(cstage[i] >> 32)) - KEYBASE) >> 16)], 1u);
    } else {
      for (int s = tid; s < NSLOTS; s += 256) {
        int t = s >> 6, j = s & 63;
        if (j < (int)tc[t])
          atomicAdd(&hist4[wb + ((((unsigned)(crow[s] >> 32)) - KEYBASE) >> 16)], 1u);
      }
    }
    __syncthreads();
    unsigned v1 = hist4[tid] + hist4[tid + 256] + hist4[tid + 512] + hist4[tid + 768];
    v1 = wave_sufscan(v1, lane);
    if (lane == 0) wtot[wv] = v1;
    __syncthreads();
    { unsigned add = 0; for (int w = wv + 1; w < 4; ++w) add += wtot[w]; v1 += add; }
    suf[tid] = v1;
    hist4[tid] = 0;                            // re-zero [0..256) as per-bucket alloc
    __syncthreads();
    { unsigned nxt = (tid == 255) ? 0u : suf[tid + 1];
      if (v1 >= KSEL && nxt < KSEL) {
        s_sel[0] = (unsigned)tid;              // boundary byte B1
        s_sel[1] = nxt;                        // n_gt
        s_sel[2] = v1 - nxt;                   // m (count in bucket B1)
      } }
    __syncthreads();
    const unsigned B1 = s_sel[0];
    const int n_gt = (int)s_sel[1];
    const int need = KSEL - n_gt;
    // scatter compaction: per-bucket allocators (independent short chains)
    if (staged) {
      for (int i = tid; i < cnt; i += 256) {
        ull v = cstage[i];
        unsigned bkt = (((unsigned)(v >> 32)) - KEYBASE) >> 16;
        if (bkt > B1) {
          unsigned above = (bkt == 255u) ? 0u : suf[bkt + 1];
          unsigned p = above + atomicAdd(&hist4[bkt], 1u);
          if (p < KSEL) cand[p] = v;
        } else if (bkt == B1) {
          unsigned p = atomicAdd(&hist4[bkt], 1u);
          if (p < KSEL) tie[p] = v;
        }
      }
    } else {
      for (int s = tid; s < NSLOTS; s += 256) {
        int t = s >> 6, j = s & 63;
        if (j < (int)tc[t]) {
          ull v = crow[s];
          unsigned bkt = (((unsigned)(v >> 32)) - KEYBASE) >> 16;
          if (bkt > B1) {
            unsigned above = (bkt == 255u) ? 0u : suf[bkt + 1];
            unsigned p = above + atomicAdd(&hist4[bkt], 1u);
            if (p < KSEL) cand[p] = v;
          } else if (bkt == B1) {
            unsigned p = atomicAdd(&hist4[bkt], 1u);
            if (p < KSEL) tie[p] = v;
          }
        }
      }
    }
    __syncthreads();
    // exact rank inside boundary bucket (by full value desc => key desc, idx asc)
    { int m = (int)s_sel[2]; if (m > KSEL) m = KSEL;
      if (tid < m) {
        ull e = tie[tid]; int rank = 0;
        for (int i2 = 0; i2 < m; ++i2) rank += (tie[i2] > e) ? 1 : 0;
        if (rank < need) cand[n_gt + rank] = e;
      } }
    __syncthreads();
  }

  // bitonic sort 256 descending: registers + shfl; LDS only for j>=64
  ull v = cand[tid];
  for (int kk = 2; kk <= KSEL; kk <<= 1) {
    for (int j = kk >> 1; j > 0; j >>= 1) {
      ull o;
      if (j >= 64) {
        cand[tid] = v;
        __syncthreads();
        o = cand[tid ^ j];
        __syncthreads();
      } else {
        o = shflxor64(v, j);
      }
      bool keep_max = (((tid & j) == 0) == ((tid & kk) == 0));
      v = keep_max ? (v > o ? v : o) : (v < o ? v : o);
    }
  }
  __syncthreads();   // cstage dead from here; supp/cbox aliases safe

  {
    float4 bx = make_float4(0.f, 0.f, 0.f, 0.f);
    if (v != 0ull) {
      int myn = (int)(~(unsigned)v) & 0x3FFF;
      const float* bp;
      if (myn < NA1)            bp = b1 + (size_t)(b * NA1 + myn) * 4;
      else if (myn < NA1 + NA2) bp = b2 + (size_t)(b * NA2 + (myn - NA1)) * 4;
      else                      bp = b3 + (size_t)(b * NA3 + (myn - NA1 - NA2)) * 4;
      bx = *(const float4*)bp;
    }
    cbox[tid] = bx;
  }
  ull mvalid = __ballot(v != 0ull);
  if (lane == 0) kw[wv] = mvalid;
  __syncthreads();

  // suppression rows (thread i: bits j>i with iou>thr) — fixed trip, unrolled
  {
    const float4 mb = cbox[tid];
    const float myarea = (mb.z - mb.x) * (mb.w - mb.y);
    ull m0 = 0, m1 = 0, m2 = 0, m3 = 0;
    #pragma unroll 8
    for (int j = 0; j < KSEL; ++j) {
      float4 bj = cbox[j];
      float ja = (bj.z - bj.x) * (bj.w - bj.y);
      float iy = fmaxf(fminf(bj.z, mb.z) - fmaxf(bj.x, mb.x), 0.0f);
      float ix = fmaxf(fminf(bj.w, mb.w) - fmaxf(bj.y, mb.y), 0.0f);
      float inter = iy * ix;
      float uni = ja + myarea - inter;
      bool sup = (j > tid) && (uni > 0.0f) && (inter > IOUTHR * uni);
      ull bit = sup ? (1ull << (j & 63)) : 0ull;
      if ((j >> 6) == 0) m0 |= bit; else if ((j >> 6) == 1) m1 |= bit;
      else if ((j >> 6) == 2) m2 |= bit; else m3 |= bit;
    }
    supp[tid * 5 + 0] = m0; supp[tid * 5 + 1] = m1;
    supp[tid * 5 + 2] = m2; supp[tid * 5 + 3] = m3;
  }
  __syncthreads();

  // greedy scan, wave 0, registers only; early break at 100 kept (R9-measured)
  if (wv == 0) {
    ull r0[4], r1[4], r2[4], r3[4];
    #pragma unroll
    for (int w = 0; w < 4; ++w) {
      r0[w] = supp[(lane) * 5 + w];
      r1[w] = supp[(64 + lane) * 5 + w];
      r2[w] = supp[(128 + lane) * 5 + w];
      r3[w] = supp[(192 + lane) * 5 + w];
    }
    ull k0 = kw[0], k1 = kw[1], k2 = kw[2], k3 = kw[3];
    ull f0 = 0, f1 = 0, f2 = 0, f3 = 0;
    int run = 0;
#define SCAN_CHUNK(R, KT, FT)                                              \
    if (KT) for (int ib = 0; ib < 64; ++ib) {                              \
      if ((KT >> ib) & 1ull) {                                             \
        k0 &= ~bcast64(R[0], ib); k1 &= ~bcast64(R[1], ib);                \
        k2 &= ~bcast64(R[2], ib); k3 &= ~bcast64(R[3], ib);                \
        FT |= (1ull << ib);                                                \
        if (++run == MAXPC) goto scan_done;                                \
      }                                                                    \
    }
    SCAN_CHUNK(r0, k0, f0)
    SCAN_CHUNK(r1, k1, f1)
    SCAN_CHUNK(r2, k2, f2)
    SCAN_CHUNK(r3, k3, f3)
#undef SCAN_CHUNK
scan_done:
    if (lane == 0) { kfw[0] = f0; kfw[1] = f1; kfw[2] = f2; kfw[3] = f3; }
  }
  __syncthreads();

  // compact kept entries rank-sorted to g_ks
  {
    ull w0 = kfw[0], w1 = kfw[1], w2 = kfw[2], w3 = kfw[3];
    int wq = tid >> 6, wb2 = tid & 63;
    ull myw = (wq == 0) ? w0 : (wq == 1) ? w1 : (wq == 2) ? w2 : w3;
    bool kept = (myw >> wb2) & 1ull;
    if (kept) {
      ull lt = (wb2 == 0) ? 0ull : (myw & ((1ull << wb2) - 1ull));
      int rank = __popcll(lt);
      if (wq > 0) rank += __popcll(w0);
      if (wq > 1) rank += __popcll(w1);
      if (wq > 2) rank += __popcll(w2);
      unsigned key24 = (unsigned)(v >> 32) - KEYBASE;
      unsigned n = (~(unsigned)v) & 0x3FFFu;
      ull e = ((ull)key24 << 40) | ((ull)(unsigned)(127 - c) << 33) |
              ((ull)(unsigned)(255 - tid) << 25) | n;
      g_ks[(size_t)bc * MAXPC + rank] = e;
    }
    if (tid == 0)
      g_kcnt[bc] = (unsigned)(__popcll(w0) + __popcll(w1) + __popcll(w2) + __popcll(w3));
  }
}

// ---------- Kernel C: per-image merge of 80 classes -> top-100 + output ----------
__global__ __launch_bounds__(256)
void nms_final(const float* __restrict__ b1, const float* __restrict__ b2,
               const float* __restrict__ b3, float* __restrict__ out)
{
  const int tid = threadIdx.x;
  const int lane = tid & 63, wv = tid >> 6;
  const int b = blockIdx.x;
  __shared__ ull le[NC * MAXPC];               // 64000 B
  __shared__ ull cand[128];
  __shared__ ull tie[512];
  __shared__ unsigned kc[NC], ko[NC + 1];
  __shared__ unsigned hist4[1024], suf[256];
  __shared__ unsigned s_sel[4], wtot[4];

  if (tid < NC) kc[tid] = g_kcnt[b * NC + tid];
  if (tid < 128) cand[tid] = 0ull;
  __syncthreads();

  if (wv == 0) {                               // exclusive prefix over 80 counts
    unsigned carry = 0;
    for (int ch = 0; ch < 2; ++ch) {
      int idx = ch * 64 + lane;
      unsigned x = (idx < NC) ? kc[idx] : 0u;
      unsigned v = x;
      #pragma unroll
      for (int o = 1; o < 64; o <<= 1) {
        unsigned t2 = __shfl_up(v, o, 64);
        if (lane >= o) v += t2;
      }
      if (idx < NC) ko[idx] = carry + v - x;
      carry += (unsigned)__shfl((int)v, 63, 64);
    }
    if (lane == 0) ko[NC] = carry;
  }
  __syncthreads();
  const int total = (int)ko[NC];
  const bool take_all = (total <= MAXTOT);

  // staging: 8-wide batched, precomputed offsets
  const ull* krow = g_ks + (size_t)b * NC * MAXPC;
  for (int base = 0; base < NC * MAXPC; base += 2048) {
    ull v[8]; int pos[8]; bool ok[8];
    #pragma unroll
    for (int e = 0; e < 8; ++e) {
      int s = base + e * 256 + tid;
      ok[e] = false;
      if (s < NC * MAXPC) {
        int cc = s / MAXPC, j = s - cc * MAXPC;
        if (j < (int)kc[cc]) { ok[e] = true; pos[e] = (int)ko[cc] + j; v[e] = krow[s]; }
      }
    }
    #pragma unroll
    for (int e = 0; e < 8; ++e)
      if (ok[e]) le[pos[e]] = v[e];
  }
  __syncthreads();

  if (take_all) {
    if (tid < total) cand[tid] = le[tid];
    __syncthreads();
  } else {
    // one-pass byte histogram (entry>>56 == key24>>16)
    hist4[tid] = 0; hist4[tid + 256] = 0; hist4[tid + 512] = 0; hist4[tid + 768] = 0;
    __syncthreads();
    const int wb = wv << 8;
    for (int i = tid; i < total; i += 256)
      atomicAdd(&hist4[wb + (unsigned)(le[i] >> 56)], 1u);
    __syncthreads();
    unsigned v1 = hist4[tid] + hist4[tid + 256] + hist4[tid + 512] + hist4[tid + 768];
    v1 = wave_sufscan(v1, lane);
    if (lane == 0) wtot[wv] = v1;
    __syncthreads();
    { unsigned add = 0; for (int w = wv + 1; w < 4; ++w) add += wtot[w]; v1 += add; }
    suf[tid] = v1;
    hist4[tid] = 0;                            // alloc re-zero
    __syncthreads();
    { unsigned nxt = (tid == 255) ? 0u : suf[tid + 1];
      if (v1 >= MAXTOT && nxt < MAXTOT) {
        s_sel[0] = (unsigned)tid; s_sel[1] = nxt; s_sel[2] = v1 - nxt;
      } }
    __syncthreads();
    const unsigned B1 = s_sel[0];
    const int n_gt = (int)s_sel[1];
    const int need = MAXTOT - n_gt;
    for (int i = tid; i < total; i += 256) {
      ull v = le[i];
      unsigned bkt = (unsigned)(v >> 56);
      if (bkt > B1) {
        unsigned above = (bkt == 255u) ? 0u : suf[bkt + 1];
        unsigned p = above + atomicAdd(&hist4[bkt], 1u);
        if (p < 128u) cand[p] = v;
      } else if (bkt == B1) {
        unsigned p = atomicAdd(&hist4[bkt], 1u);
        if (p < 512u) tie[p] = v;
      }
    }
    __syncthreads();
    { int m = (int)s_sel[2]; if (m > 512) m = 512;
      if (tid < m) {
        ull e = tie[tid]; int rank = 0;
        for (int i2 = 0; i2 < m; ++i2) rank += (tie[i2] > e) ? 1 : 0;
        if (rank < need) cand[n_gt + rank] = e;
      }
      for (int i = 256 + tid; i < m; i += 256) {
        ull e = tie[i]; int rank = 0;
        for (int i2 = 0; i2 < m; ++i2) rank += (tie[i2] > e) ? 1 : 0;
        if (rank < need) cand[n_gt + rank] = e;
      } }
    __syncthreads();
  }

  // bitonic sort 128 descending
  for (int kk = 2; kk <= 128; kk <<= 1) {
    for (int j = kk >> 1; j > 0; j >>= 1) {
      if (tid < 128) {
        int ixj = tid ^ j;
        if (ixj > tid) {
          ull a = cand[tid], c2 = cand[ixj];
          if (((tid & kk) == 0) ? (a < c2) : (a > c2)) { cand[tid] = c2; cand[ixj] = a; }
        }
      }
      __syncthreads();
    }
  }

  if (tid < MAXTOT) {
    ull e = cand[tid];
    float o0 = 0.f, o1 = 0.f, o2 = 0.f, o3 = 0.f, osc = 0.f, ocl = 0.f;
    if (e != 0ull) {
      unsigned key24 = (unsigned)(e >> 40);
      float sc = inv_okey(key24 + KEYBASE);
      int cls = 127 - (int)((e >> 33) & 127u);
      int n = (int)(e & 0x3FFFu);
      const float* bp;
      if (n < NA1)            bp = b1 + (size_t)(b * NA1 + n) * 4;
      else if (n < NA1 + NA2) bp = b2 + (size_t)(b * NA2 + (n - NA1)) * 4;
      else                    bp = b3 + (size_t)(b * NA3 + (n - NA1 - NA2)) * 4;
      float4 bx = *(const float4*)bp;
      o0 = fminf(fmaxf(bx.x, 0.0f), 1.0f);
      o1 = fminf(fmaxf(bx.y, 0.0f), 1.0f);
      o2 = fminf(fmaxf(bx.z, 0.0f), 1.0f);
      o3 = fminf(fmaxf(bx.w, 0.0f), 1.0f);
      osc = sc; ocl = (float)cls;
    }
    int oi = b * MAXTOT + tid;
    out[(size_t)oi * 4 + 0] = o0;
    out[(size_t)oi * 4 + 1] = o1;
    out[(size_t)oi * 4 + 2] = o2;
    out[(size_t)oi * 4 + 3] = o3;
    out[BATCH * MAXTOT * 4 + oi] = osc;
    out[BATCH * MAXTOT * 5 + oi] = ocl;
  }
  if (tid == 0) out[BATCH * MAXTOT * 6 + b] = (float)(total < MAXTOT ? total : MAXTOT);
}

extern "C" void kernel_launch(void* const* d_in, const int* in_sizes, int n_in,
                              void* d_out, int out_size, void* d_ws, size_t ws_size,
                              hipStream_t stream) {
  const float* b1 = (const float*)d_in[0];
  const float* c1 = (const float*)d_in[1];
  const float* p1 = (const float*)d_in[2];
  const float* b2 = (const float*)d_in[3];
  const float* c2 = (const float*)d_in[4];
  const float* p2 = (const float*)d_in[5];
  const float* b3 = (const float*)d_in[6];
  const float* c3 = (const float*)d_in[7];
  const float* p3 = (const float*)d_in[8];
  (void)in_sizes; (void)n_in; (void)out_size; (void)d_ws; (void)ws_size;

  score_compact<<<dim3(BATCH * NTILES), dim3(256), 0, stream>>>(c1, p1, c2, p2, c3, p3);
  nms_per_class<<<dim3(BATCH * NC), dim3(256), 0, stream>>>(b1, b2, b3);
  nms_final<<<dim3(BATCH), dim3(256), 0, stream>>>(b1, b2, b3, (float*)d_out);
}